// Round 7
// baseline (587.485 us; speedup 1.0000x reference)
//
#include <hip/hip_runtime.h>
#include <stdint.h>

// R13: base = R12 except attn work decomposition. Each block now owns the
// COMPLEMENTARY q-tile pair (qtA=g, qtB=31-g), g=0..15: exactly 33
// compute-units per block (uniform -> no residency decay, all blocks finish
// together), 1024 blocks = 4/CU exactly. Since qtA's j-range is a subset of
// qtB's, tile A rides on tile B's staged K/V tiles -- staging per unit of
// compute halves. LDS unchanged 18.4KB (P in-register since R10).
// __launch_bounds__(256,4) caps VGPR at 128 => guaranteed 4 blocks/CU.

typedef unsigned short u16;
typedef short bf16x8 __attribute__((ext_vector_type(8)));
typedef float f32x4 __attribute__((ext_vector_type(4)));

#define D_MODEL 2048
#define QKV_DIM 3072
#define NUM_HEADS 32
#define HEAD_DIM 64
#define SEQ 2048
#define MTOT 4096

static __device__ __forceinline__ u16 f2bf(float f){
  uint32_t u = __builtin_bit_cast(uint32_t, f);
  u += 0x7FFFu + ((u >> 16) & 1u);
  return (u16)(u >> 16);
}

static __device__ __forceinline__ float exp2_fast(float x){
  float r;
  asm("v_exp_f32 %0, %1" : "=v"(r) : "v"(x));
  return r;
}

static __device__ __forceinline__ uint32_t cvt_pk_bf16(float lo, float hi){
  uint32_t r;
  asm("v_cvt_pk_bf16_f32 %0, %1, %2" : "=v"(r) : "v"(lo), "v"(hi));
  return r;
}

static __device__ __forceinline__ void gload16(const u16* g, u16* l){
  __builtin_amdgcn_global_load_lds(
      (__attribute__((address_space(1))) uint32_t*)(uintptr_t)g,
      (__attribute__((address_space(3))) uint32_t*)l,
      16, 0, 0);
}

__global__ __launch_bounds__(256)
void cvt_bf16(const float* __restrict__ in, u16* __restrict__ out, int n){
  const int i = (blockIdx.x * 256 + threadIdx.x) * 8;
  if (i >= n) return;
  float4 a = *(const float4*)(in + i);
  float4 b = *(const float4*)(in + i + 4);
  union { u16 h[8]; uint4 v; } t;
  t.h[0]=f2bf(a.x); t.h[1]=f2bf(a.y); t.h[2]=f2bf(a.z); t.h[3]=f2bf(a.w);
  t.h[4]=f2bf(b.x); t.h[5]=f2bf(b.y); t.h[6]=f2bf(b.z); t.h[7]=f2bf(b.w);
  *(uint4*)(out + i) = t.v;
}

// C[M,N] = A[M,K] @ B[N,K]^T (m97 structure, unchanged).
template <bool F32OUT>
__global__ __launch_bounds__(256)
void gemm_bt(const u16* __restrict__ A, const u16* __restrict__ B,
             void* __restrict__ Cv, int M, int N, int K){
  constexpr int BK = 32;
  __shared__ __attribute__((aligned(16))) u16 As[128*BK];
  __shared__ __attribute__((aligned(16))) u16 Bs[128*BK];
  const int tid  = threadIdx.x;
  const int wave = tid >> 6, lane = tid & 63;
  const int quad = lane >> 4, l16 = lane & 15;
  const int wrow = wave >> 1, wcol = wave & 1;
  const int m0 = blockIdx.y * 128, n0 = blockIdx.x * 128;
  const int srow = lane >> 2, scol = (lane & 3) * 8;

  const f32x4 zero = {0.f, 0.f, 0.f, 0.f};
  f32x4 acc[4][4];
#pragma unroll
  for (int i = 0; i < 4; i++)
#pragma unroll
    for (int j = 0; j < 4; j++) acc[i][j] = zero;

  for (int k0 = 0; k0 < K; k0 += BK){
#pragma unroll
    for (int t = 0; t < 2; t++){
      const int chunk = wave + t*4;
      gload16(A + (size_t)(m0 + chunk*16 + srow)*K + k0 + scol, As + chunk*16*BK);
      gload16(B + (size_t)(n0 + chunk*16 + srow)*K + k0 + scol, Bs + chunk*16*BK);
    }
    __syncthreads();
    bf16x8 af[4], bfr[4];
#pragma unroll
    for (int mi = 0; mi < 4; mi++)
      af[mi] = *(const bf16x8*)(As + (wrow*64 + mi*16 + l16)*BK + quad*8);
#pragma unroll
    for (int ni = 0; ni < 4; ni++)
      bfr[ni] = *(const bf16x8*)(Bs + (wcol*64 + ni*16 + l16)*BK + quad*8);
#pragma unroll
    for (int mi = 0; mi < 4; mi++)
#pragma unroll
      for (int ni = 0; ni < 4; ni++)
        acc[mi][ni] = __builtin_amdgcn_mfma_f32_16x16x32_bf16(af[mi], bfr[ni], acc[mi][ni], 0, 0, 0);
    __syncthreads();
  }
#pragma unroll
  for (int mi = 0; mi < 4; mi++)
#pragma unroll
    for (int ni = 0; ni < 4; ni++){
      const int col = n0 + wcol*64 + ni*16 + l16;
#pragma unroll
      for (int r = 0; r < 4; r++){
        const int row = m0 + wrow*64 + mi*16 + quad*4 + r;
        if constexpr (F32OUT)
          ((float*)Cv)[(size_t)row*N + col] = acc[mi][ni][r];
        else
          ((u16*)Cv)[(size_t)row*N + col] = f2bf(acc[mi][ni][r]);
      }
    }
}

// V^T pre-transpose with PV k-order permutation baked into the column order:
// within each 64-key tile, column (32*ss + 8*q + 4*ni' + r) holds key
// ((2*ss+ni')*16 + q*4 + r).
__global__ __launch_bounds__(256)
void vtrans(const u16* __restrict__ QKV, u16* __restrict__ VT){
  __shared__ u16 Ls[64*72];
  const int tid = threadIdx.x;
  const int st = blockIdx.x, hk = blockIdx.y, b = blockIdx.z;
  const size_t rb = (size_t)b * SEQ;
#pragma unroll
  for (int t = 0; t < 2; t++){
    const int task = t*256 + tid;
    const int r = task >> 3, c = task & 7;
    *(uint4*)(Ls + r*72 + c*8) =
        *(const uint4*)(QKV + (rb + st*64 + r)*QKV_DIM + 2560 + hk*HEAD_DIM + c*8);
  }
  __syncthreads();
  u16* vt_g = VT + ((size_t)(b*8 + hk) * 64) * SEQ;
#pragma unroll
  for (int t = 0; t < 2; t++){
    const int task = t*256 + tid;
    const int d = task >> 3, sc = task & 7;
    union { u16 h[8]; uint4 v; } tmp;
#pragma unroll
    for (int e = 0; e < 8; e++){
      const int key = ((2*(sc>>2) + (e>>2))<<4) + ((sc&3)<<2) + (e&3);
      tmp.h[e] = Ls[key*72 + d];
    }
    *(uint4*)(vt_g + (size_t)d*SEQ + st*64 + sc*8) = tmp.v;
  }
}

// one q-tile's compute vs the currently staged K/V tile: QK^T (swapped),
// log2-softmax with defer-max, in-register P, PV accumulate.
static __device__ __forceinline__ void tile_step(
    const u16* __restrict__ Ks, const u16* __restrict__ Vt,
    const bf16x8* qf, f32x4* oacc, float& m_i, float& l_i,
    int quad, int l16, bool diag, int qrow){
  constexpr int KP = 72;
  const f32x4 zero = {0.f, 0.f, 0.f, 0.f};
  const float SCL = 0.125f * 1.44269504f;
  f32x4 st[4];
#pragma unroll
  for (int ni = 0; ni < 4; ni++){
    f32x4 s = zero;
#pragma unroll
    for (int ss = 0; ss < 2; ss++){
      bf16x8 kf = *(const bf16x8*)(Ks + (ni*16 + l16)*KP + ss*32 + quad*8);
      s = __builtin_amdgcn_mfma_f32_16x16x32_bf16(kf, qf[ss], s, 0, 0, 0);
    }
#pragma unroll
    for (int r = 0; r < 4; r++) st[ni][r] = s[r] * SCL;
  }
  if (diag){
#pragma unroll
    for (int ni = 0; ni < 4; ni++)
#pragma unroll
      for (int r = 0; r < 4; r++)
        if (ni*16 + quad*4 + r > qrow) st[ni][r] = -INFINITY;
  }
  float mx = fmaxf(fmaxf(fmaxf(st[0][0], st[0][1]), fmaxf(st[0][2], st[0][3])),
                   fmaxf(fmaxf(st[1][0], st[1][1]), fmaxf(st[1][2], st[1][3])));
  mx = fmaxf(mx, fmaxf(fmaxf(fmaxf(st[2][0], st[2][1]), fmaxf(st[2][2], st[2][3])),
                       fmaxf(fmaxf(st[3][0], st[3][1]), fmaxf(st[3][2], st[3][3]))));
  mx = fmaxf(mx, __shfl_xor(mx, 16));
  mx = fmaxf(mx, __shfl_xor(mx, 32));

  if (__all(mx <= m_i + 10.f)){
    float ps = 0.f;
#pragma unroll
    for (int ni = 0; ni < 4; ni++)
#pragma unroll
      for (int r = 0; r < 4; r++){
        const float p = exp2_fast(st[ni][r] - m_i);
        st[ni][r] = p;
        ps += p;
      }
    ps += __shfl_xor(ps, 16);
    ps += __shfl_xor(ps, 32);
    l_i += ps;
  } else {
    const float mn = fmaxf(m_i, mx);
    const float alpha = exp2_fast(m_i - mn);
    float ps = 0.f;
#pragma unroll
    for (int ni = 0; ni < 4; ni++)
#pragma unroll
      for (int r = 0; r < 4; r++){
        const float p = exp2_fast(st[ni][r] - mn);
        st[ni][r] = p;
        ps += p;
      }
    ps += __shfl_xor(ps, 16);
    ps += __shfl_xor(ps, 32);
    l_i = l_i*alpha + ps;
    m_i = mn;
    float ar[4];
#pragma unroll
    for (int r = 0; r < 4; r++) ar[r] = __shfl(alpha, quad*4 + r);
#pragma unroll
    for (int ci = 0; ci < 4; ci++)
#pragma unroll
      for (int r = 0; r < 4; r++) oacc[ci][r] *= ar[r];
  }

  bf16x8 pfr[2];
#pragma unroll
  for (int ss = 0; ss < 2; ss++){
    union { uint32_t w[4]; bf16x8 v; } pk;
    pk.w[0] = cvt_pk_bf16(st[2*ss][0],   st[2*ss][1]);
    pk.w[1] = cvt_pk_bf16(st[2*ss][2],   st[2*ss][3]);
    pk.w[2] = cvt_pk_bf16(st[2*ss+1][0], st[2*ss+1][1]);
    pk.w[3] = cvt_pk_bf16(st[2*ss+1][2], st[2*ss+1][3]);
    pfr[ss] = pk.v;
  }
#pragma unroll
  for (int ss = 0; ss < 2; ss++)
#pragma unroll
    for (int ci = 0; ci < 4; ci++){
      bf16x8 vf = *(const bf16x8*)(Vt + (ci*16 + l16)*KP + ss*32 + quad*8);
      oacc[ci] = __builtin_amdgcn_mfma_f32_16x16x32_bf16(pfr[ss], vf, oacc[ci], 0, 0, 0);
    }
}

// attn: complementary-pair blocks, swapped QK^T, in-register P, reg-prefetch.
__global__ __launch_bounds__(256, 4)
void attn(const u16* __restrict__ Q, const u16* __restrict__ Kp,
          const u16* __restrict__ VT, u16* __restrict__ O, int qs, int ks){
  constexpr int KP = 72;
  __shared__ __attribute__((aligned(16))) u16 Ks[64*KP];
  __shared__ __attribute__((aligned(16))) u16 Vt[64*KP];
  const int tid = threadIdx.x;
  const int wave = tid >> 6, lane = tid & 63, quad = lane >> 4, l16 = lane & 15;
  const int g_ = blockIdx.x;            // 0..15
  const int qtA = g_, qtB = 31 - g_;    // qtA <= 15 < qtB; A's range ⊂ B's
  const int h = blockIdx.y, b = blockIdx.z;
  const int hk = h >> 2;
  const size_t rb = (size_t)b * SEQ;
  const u16* vt_g = VT + ((size_t)(b*8 + hk) * 64) * SEQ;

  const int sr = tid >> 2, sc = tid & 3;
  const int qrow = wave*16 + l16;

  bf16x8 qfA[2], qfB[2];
  {
    const u16* qpA = Q + (rb + qtA*64 + wave*16 + l16)*qs + h*HEAD_DIM;
    qfA[0] = *(const bf16x8*)(qpA + quad*8);
    qfA[1] = *(const bf16x8*)(qpA + 32 + quad*8);
    const u16* qpB = Q + (rb + qtB*64 + wave*16 + l16)*qs + h*HEAD_DIM;
    qfB[0] = *(const bf16x8*)(qpB + quad*8);
    qfB[1] = *(const bf16x8*)(qpB + 32 + quad*8);
  }
  const f32x4 zero = {0.f, 0.f, 0.f, 0.f};
  f32x4 oA[4], oB[4];
#pragma unroll
  for (int i = 0; i < 4; i++){ oA[i] = zero; oB[i] = zero; }
  float mA = -INFINITY, lA = 0.f, mB = -INFINITY, lB = 0.f;

  uint4 kreg0, kreg1, vreg0, vreg1;
  {
    const u16* kg = Kp + (rb + sr)*ks + hk*HEAD_DIM;
    kreg0 = *(const uint4*)(kg + sc*8);
    kreg1 = *(const uint4*)(kg + (sc+4)*8);
    const u16* vg = vt_g + (size_t)sr*SEQ;
    vreg0 = *(const uint4*)(vg + sc*8);
    vreg1 = *(const uint4*)(vg + (sc+4)*8);
  }

  for (int j = 0; j <= qtB; ++j){
    *(uint4*)(Ks + sr*KP + sc*8)     = kreg0;
    *(uint4*)(Ks + sr*KP + (sc+4)*8) = kreg1;
    *(uint4*)(Vt + sr*KP + sc*8)     = vreg0;
    *(uint4*)(Vt + sr*KP + (sc+4)*8) = vreg1;
    __syncthreads();
    if (j < qtB){
      const u16* kg = Kp + (rb + (j+1)*64 + sr)*ks + hk*HEAD_DIM;
      kreg0 = *(const uint4*)(kg + sc*8);
      kreg1 = *(const uint4*)(kg + (sc+4)*8);
      const u16* vg = vt_g + (size_t)sr*SEQ + (j+1)*64;
      vreg0 = *(const uint4*)(vg + sc*8);
      vreg1 = *(const uint4*)(vg + (sc+4)*8);
    }

    tile_step(Ks, Vt, qfB, oB, mB, lB, quad, l16, j == qtB, qrow);
    if (j <= qtA)
      tile_step(Ks, Vt, qfA, oA, mA, lA, quad, l16, j == qtA, qrow);
    __syncthreads();
  }

  float lfA[4], lfB[4];
#pragma unroll
  for (int r = 0; r < 4; r++){
    lfA[r] = __shfl(lA, quad*4 + r);
    lfB[r] = __shfl(lB, quad*4 + r);
  }
#pragma unroll
  for (int ci = 0; ci < 4; ci++)
#pragma unroll
    for (int r = 0; r < 4; r++){
      const size_t rowA = rb + qtA*64 + wave*16 + quad*4 + r;
      O[rowA*D_MODEL + h*HEAD_DIM + ci*16 + l16] = f2bf(oA[ci][r] / lfA[r]);
      const size_t rowB = rb + qtB*64 + wave*16 + quad*4 + r;
      O[rowB*D_MODEL + h*HEAD_DIM + ci*16 + l16] = f2bf(oB[ci][r] / lfB[r]);
    }
}

extern "C" void kernel_launch(void* const* d_in, const int* in_sizes, int n_in,
                              void* d_out, int out_size, void* d_ws, size_t ws_size,
                              hipStream_t stream){
  const float* x  = (const float*)d_in[0];
  const float* Wq = (const float*)d_in[1];
  const float* Wk = (const float*)d_in[2];
  const float* Wv = (const float*)d_in[3];
  const float* Wo = (const float*)d_in[4];
  float* out = (float*)d_out;

  u16* xb   = (u16*)d_ws;                    // x / later attn-out  [4096,2048]
  u16* Wb   = xb + (size_t)MTOT*D_MODEL;     // fused weights [3072,2048]
  u16* VTb  = Wb + (size_t)QKV_DIM*D_MODEL;  // V^T [16*64, 2048] (own slot)
  u16* QKVb = (u16*)d_out;                   // QKV scratch [4096,3072] bf16

  const int nx  = MTOT*D_MODEL;
  const int nwq = D_MODEL*D_MODEL;
  const int nwk = 512*D_MODEL;

  cvt_bf16<<<nx/2048, 256, 0, stream>>>(x, xb, nx);
  cvt_bf16<<<nwq/2048, 256, 0, stream>>>(Wq, Wb, nwq);
  cvt_bf16<<<nwk/2048, 256, 0, stream>>>(Wk, Wb + (size_t)D_MODEL*D_MODEL, nwk);
  cvt_bf16<<<nwk/2048, 256, 0, stream>>>(Wv, Wb + (size_t)2560*D_MODEL, nwk);
  gemm_bt<false><<<dim3(QKV_DIM/128, MTOT/128), 256, 0, stream>>>(xb, Wb, QKVb, MTOT, QKV_DIM, D_MODEL);
  vtrans<<<dim3(SEQ/64, 8, 2), 256, 0, stream>>>(QKVb, VTb);
  attn<<<dim3(16, NUM_HEADS, 2), 256, 0, stream>>>(
      QKVb, QKVb + D_MODEL, VTb, xb, QKV_DIM, QKV_DIM);
  cvt_bf16<<<nwq/2048, 256, 0, stream>>>(Wo, Wb, nwq);
  gemm_bt<true><<<dim3(D_MODEL/128, MTOT/128), 256, 0, stream>>>(xb, Wb, (void*)out, MTOT, D_MODEL, D_MODEL);
}

// Round 8
// 346.738 us; speedup vs baseline: 1.6943x; 1.6943x over previous
//
#include <hip/hip_runtime.h>
#include <stdint.h>

// R14: revert R13's catastrophic pairing (launch_bounds cap -> 567MB scratch
// spill traffic). Base = R12 (attn 109us, total 347us) with two SUBTRACTIVE
// edits aimed at the 64-VGPR occupancy boundary (waves/CU doubles at <=64):
//  1. Drop the 16 persistent prefetch VGPRs (R7 proved prefetch is neutral:
//     staging latency is hidden by cross-block TLP). Stage global->LDS
//     directly with transient temps. Expected VGPR 76 -> ~60 => 8 blocks/CU.
//  2. Pre-scale Wq by 0.125*log2e at cvt time -- the QK scale rides the
//     GEMM; deletes 16 VALU muls/iter from attn's serial chain.
// No launch_bounds forcing (R13 lesson: caps + fat state = spill disaster).

typedef unsigned short u16;
typedef short bf16x8 __attribute__((ext_vector_type(8)));
typedef float f32x4 __attribute__((ext_vector_type(4)));

#define D_MODEL 2048
#define QKV_DIM 3072
#define NUM_HEADS 32
#define HEAD_DIM 64
#define SEQ 2048
#define MTOT 4096

static __device__ __forceinline__ u16 f2bf(float f){
  uint32_t u = __builtin_bit_cast(uint32_t, f);
  u += 0x7FFFu + ((u >> 16) & 1u);
  return (u16)(u >> 16);
}

static __device__ __forceinline__ float exp2_fast(float x){
  float r;
  asm("v_exp_f32 %0, %1" : "=v"(r) : "v"(x));
  return r;
}

static __device__ __forceinline__ uint32_t cvt_pk_bf16(float lo, float hi){
  uint32_t r;
  asm("v_cvt_pk_bf16_f32 %0, %1, %2" : "=v"(r) : "v"(lo), "v"(hi));
  return r;
}

static __device__ __forceinline__ void gload16(const u16* g, u16* l){
  __builtin_amdgcn_global_load_lds(
      (__attribute__((address_space(1))) uint32_t*)(uintptr_t)g,
      (__attribute__((address_space(3))) uint32_t*)l,
      16, 0, 0);
}

__global__ __launch_bounds__(256)
void cvt_bf16(const float* __restrict__ in, u16* __restrict__ out, int n,
              float scl){
  const int i = (blockIdx.x * 256 + threadIdx.x) * 8;
  if (i >= n) return;
  float4 a = *(const float4*)(in + i);
  float4 b = *(const float4*)(in + i + 4);
  union { u16 h[8]; uint4 v; } t;
  t.h[0]=f2bf(a.x*scl); t.h[1]=f2bf(a.y*scl); t.h[2]=f2bf(a.z*scl); t.h[3]=f2bf(a.w*scl);
  t.h[4]=f2bf(b.x*scl); t.h[5]=f2bf(b.y*scl); t.h[6]=f2bf(b.z*scl); t.h[7]=f2bf(b.w*scl);
  *(uint4*)(out + i) = t.v;
}

// C[M,N] = A[M,K] @ B[N,K]^T (m97 structure, unchanged).
template <bool F32OUT>
__global__ __launch_bounds__(256)
void gemm_bt(const u16* __restrict__ A, const u16* __restrict__ B,
             void* __restrict__ Cv, int M, int N, int K){
  constexpr int BK = 32;
  __shared__ __attribute__((aligned(16))) u16 As[128*BK];
  __shared__ __attribute__((aligned(16))) u16 Bs[128*BK];
  const int tid  = threadIdx.x;
  const int wave = tid >> 6, lane = tid & 63;
  const int quad = lane >> 4, l16 = lane & 15;
  const int wrow = wave >> 1, wcol = wave & 1;
  const int m0 = blockIdx.y * 128, n0 = blockIdx.x * 128;
  const int srow = lane >> 2, scol = (lane & 3) * 8;

  const f32x4 zero = {0.f, 0.f, 0.f, 0.f};
  f32x4 acc[4][4];
#pragma unroll
  for (int i = 0; i < 4; i++)
#pragma unroll
    for (int j = 0; j < 4; j++) acc[i][j] = zero;

  for (int k0 = 0; k0 < K; k0 += BK){
#pragma unroll
    for (int t = 0; t < 2; t++){
      const int chunk = wave + t*4;
      gload16(A + (size_t)(m0 + chunk*16 + srow)*K + k0 + scol, As + chunk*16*BK);
      gload16(B + (size_t)(n0 + chunk*16 + srow)*K + k0 + scol, Bs + chunk*16*BK);
    }
    __syncthreads();
    bf16x8 af[4], bfr[4];
#pragma unroll
    for (int mi = 0; mi < 4; mi++)
      af[mi] = *(const bf16x8*)(As + (wrow*64 + mi*16 + l16)*BK + quad*8);
#pragma unroll
    for (int ni = 0; ni < 4; ni++)
      bfr[ni] = *(const bf16x8*)(Bs + (wcol*64 + ni*16 + l16)*BK + quad*8);
#pragma unroll
    for (int mi = 0; mi < 4; mi++)
#pragma unroll
      for (int ni = 0; ni < 4; ni++)
        acc[mi][ni] = __builtin_amdgcn_mfma_f32_16x16x32_bf16(af[mi], bfr[ni], acc[mi][ni], 0, 0, 0);
    __syncthreads();
  }
#pragma unroll
  for (int mi = 0; mi < 4; mi++)
#pragma unroll
    for (int ni = 0; ni < 4; ni++){
      const int col = n0 + wcol*64 + ni*16 + l16;
#pragma unroll
      for (int r = 0; r < 4; r++){
        const int row = m0 + wrow*64 + mi*16 + quad*4 + r;
        if constexpr (F32OUT)
          ((float*)Cv)[(size_t)row*N + col] = acc[mi][ni][r];
        else
          ((u16*)Cv)[(size_t)row*N + col] = f2bf(acc[mi][ni][r]);
      }
    }
}

// V^T pre-transpose with PV k-order permutation baked into the column order:
// within each 64-key tile, column (32*ss + 8*q + 4*ni' + r) holds key
// ((2*ss+ni')*16 + q*4 + r).
__global__ __launch_bounds__(256)
void vtrans(const u16* __restrict__ QKV, u16* __restrict__ VT){
  __shared__ u16 Ls[64*72];
  const int tid = threadIdx.x;
  const int st = blockIdx.x, hk = blockIdx.y, b = blockIdx.z;
  const size_t rb = (size_t)b * SEQ;
#pragma unroll
  for (int t = 0; t < 2; t++){
    const int task = t*256 + tid;
    const int r = task >> 3, c = task & 7;
    *(uint4*)(Ls + r*72 + c*8) =
        *(const uint4*)(QKV + (rb + st*64 + r)*QKV_DIM + 2560 + hk*HEAD_DIM + c*8);
  }
  __syncthreads();
  u16* vt_g = VT + ((size_t)(b*8 + hk) * 64) * SEQ;
#pragma unroll
  for (int t = 0; t < 2; t++){
    const int task = t*256 + tid;
    const int d = task >> 3, sc = task & 7;
    union { u16 h[8]; uint4 v; } tmp;
#pragma unroll
    for (int e = 0; e < 8; e++){
      const int key = ((2*(sc>>2) + (e>>2))<<4) + ((sc&3)<<2) + (e&3);
      tmp.h[e] = Ls[key*72 + d];
    }
    *(uint4*)(vt_g + (size_t)d*SEQ + st*64 + sc*8) = tmp.v;
  }
}

// attn: swapped QK^T (scale pre-folded into Wq), in-register P, log2 softmax
// + defer-max, cvt_pk, complement-balanced work assignment, direct staging.
__global__ __launch_bounds__(256)
void attn(const u16* __restrict__ Q, const u16* __restrict__ Kp,
          const u16* __restrict__ VT, u16* __restrict__ O, int qs, int ks){
  constexpr int KP = 72;
  __shared__ __attribute__((aligned(16))) u16 Ks[64*KP];
  __shared__ __attribute__((aligned(16))) u16 Vt[64*KP];
  const int tid = threadIdx.x;
  const int wave = tid >> 6, lane = tid & 63, quad = lane >> 4, l16 = lane & 15;
  // complement-balanced qt across the batch dim (R12): per-CU work sums equal.
  const int g_ = (blockIdx.x + blockIdx.y) & 31;
  const int qt = blockIdx.z ? (31 - g_) : g_;
  const int h = blockIdx.y, b = blockIdx.z;
  const int hk = h >> 2;
  const size_t rb = (size_t)b * SEQ;
  const u16* vt_g = VT + ((size_t)(b*8 + hk) * 64) * SEQ;

  const int sr = tid >> 2, sc = tid & 3;
  const int qrow = wave*16 + l16;   // this lane's q-row (swapped layout)

  bf16x8 qf[2];
  {
    const u16* qp = Q + (rb + qt*64 + wave*16 + l16)*qs + h*HEAD_DIM;
    qf[0] = *(const bf16x8*)(qp + quad*8);
    qf[1] = *(const bf16x8*)(qp + 32 + quad*8);
  }
  const f32x4 zero = {0.f, 0.f, 0.f, 0.f};
  f32x4 oacc[4];
#pragma unroll
  for (int i = 0; i < 4; i++) oacc[i] = zero;
  float m_i = -INFINITY;   // running max in log2 units
  float l_i = 0.f;

  const u16* kg_base = Kp + (rb + sr)*ks + hk*HEAD_DIM;
  const u16* vg_base = vt_g + (size_t)sr*SEQ;

  for (int j = 0; j <= qt; ++j){
    // direct global->LDS staging (transient regs; latency hidden by TLP)
    {
      const u16* kg = kg_base + (size_t)(j*64)*ks;
      const u16* vg = vg_base + j*64;
      uint4 k0 = *(const uint4*)(kg + sc*8);
      uint4 k1 = *(const uint4*)(kg + (sc+4)*8);
      uint4 v0 = *(const uint4*)(vg + sc*8);
      uint4 v1 = *(const uint4*)(vg + (sc+4)*8);
      *(uint4*)(Ks + sr*KP + sc*8)     = k0;
      *(uint4*)(Ks + sr*KP + (sc+4)*8) = k1;
      *(uint4*)(Vt + sr*KP + sc*8)     = v0;
      *(uint4*)(Vt + sr*KP + (sc+4)*8) = v1;
    }
    __syncthreads();

    // QK^T swapped: st[ni][r] = S2[key = j*64 + ni*16 + quad*4 + r][qrow l16]
    // (scale already folded into Q via Wq prescale)
    f32x4 st[4];
#pragma unroll
    for (int ni = 0; ni < 4; ni++){
      f32x4 s = zero;
#pragma unroll
      for (int ss = 0; ss < 2; ss++){
        bf16x8 kf = *(const bf16x8*)(Ks + (ni*16 + l16)*KP + ss*32 + quad*8);
        s = __builtin_amdgcn_mfma_f32_16x16x32_bf16(kf, qf[ss], s, 0, 0, 0);
      }
      st[ni] = s;
    }
    if (j == qt){
#pragma unroll
      for (int ni = 0; ni < 4; ni++)
#pragma unroll
        for (int r = 0; r < 4; r++)
          if (ni*16 + quad*4 + r > qrow) st[ni][r] = -INFINITY;
    }

    // row max (16 in-lane + 2 shfl across quads)
    float mx = fmaxf(fmaxf(fmaxf(st[0][0], st[0][1]), fmaxf(st[0][2], st[0][3])),
                     fmaxf(fmaxf(st[1][0], st[1][1]), fmaxf(st[1][2], st[1][3])));
    mx = fmaxf(mx, fmaxf(fmaxf(fmaxf(st[2][0], st[2][1]), fmaxf(st[2][2], st[2][3])),
                         fmaxf(fmaxf(st[3][0], st[3][1]), fmaxf(st[3][2], st[3][3]))));
    mx = fmaxf(mx, __shfl_xor(mx, 16));
    mx = fmaxf(mx, __shfl_xor(mx, 32));

    if (__all(mx <= m_i + 10.f)){
      // defer-max: keep m_i, alpha == 1, skip rescale entirely (p <= 2^10)
      float ps = 0.f;
#pragma unroll
      for (int ni = 0; ni < 4; ni++)
#pragma unroll
        for (int r = 0; r < 4; r++){
          const float p = exp2_fast(st[ni][r] - m_i);
          st[ni][r] = p;
          ps += p;
        }
      ps += __shfl_xor(ps, 16);
      ps += __shfl_xor(ps, 32);
      l_i += ps;
    } else {
      const float mn = fmaxf(m_i, mx);
      const float alpha = exp2_fast(m_i - mn);
      float ps = 0.f;
#pragma unroll
      for (int ni = 0; ni < 4; ni++)
#pragma unroll
        for (int r = 0; r < 4; r++){
          const float p = exp2_fast(st[ni][r] - mn);
          st[ni][r] = p;
          ps += p;
        }
      ps += __shfl_xor(ps, 16);
      ps += __shfl_xor(ps, 32);
      l_i = l_i*alpha + ps;
      m_i = mn;
      float ar[4];
#pragma unroll
      for (int r = 0; r < 4; r++) ar[r] = __shfl(alpha, quad*4 + r);
#pragma unroll
      for (int ci = 0; ci < 4; ci++)
#pragma unroll
        for (int r = 0; r < 4; r++) oacc[ci][r] *= ar[r];
    }

    // P stays in registers: packed bf16 via v_cvt_pk_bf16_f32.
    bf16x8 pfr[2];
#pragma unroll
    for (int ss = 0; ss < 2; ss++){
      union { uint32_t w[4]; bf16x8 v; } pk;
      pk.w[0] = cvt_pk_bf16(st[2*ss][0],   st[2*ss][1]);
      pk.w[1] = cvt_pk_bf16(st[2*ss][2],   st[2*ss][3]);
      pk.w[2] = cvt_pk_bf16(st[2*ss+1][0], st[2*ss+1][1]);
      pk.w[3] = cvt_pk_bf16(st[2*ss+1][2], st[2*ss+1][3]);
      pfr[ss] = pk.v;
    }

#pragma unroll
    for (int ss = 0; ss < 2; ss++)
#pragma unroll
      for (int ci = 0; ci < 4; ci++){
        bf16x8 vf = *(const bf16x8*)(Vt + (ci*16 + l16)*KP + ss*32 + quad*8);
        oacc[ci] = __builtin_amdgcn_mfma_f32_16x16x32_bf16(pfr[ss], vf, oacc[ci], 0, 0, 0);
      }
    __syncthreads();
  }

  // final: l_i lives in lane-space (row=l16); broadcast to row-space
  float lf[4];
#pragma unroll
  for (int r = 0; r < 4; r++) lf[r] = __shfl(l_i, quad*4 + r);
#pragma unroll
  for (int ci = 0; ci < 4; ci++)
#pragma unroll
    for (int r = 0; r < 4; r++){
      const size_t row = rb + qt*64 + wave*16 + quad*4 + r;
      O[row*D_MODEL + h*HEAD_DIM + ci*16 + l16] = f2bf(oacc[ci][r] / lf[r]);
    }
}

extern "C" void kernel_launch(void* const* d_in, const int* in_sizes, int n_in,
                              void* d_out, int out_size, void* d_ws, size_t ws_size,
                              hipStream_t stream){
  const float* x  = (const float*)d_in[0];
  const float* Wq = (const float*)d_in[1];
  const float* Wk = (const float*)d_in[2];
  const float* Wv = (const float*)d_in[3];
  const float* Wo = (const float*)d_in[4];
  float* out = (float*)d_out;

  u16* xb   = (u16*)d_ws;                    // x / later attn-out  [4096,2048]
  u16* Wb   = xb + (size_t)MTOT*D_MODEL;     // fused weights [3072,2048]
  u16* VTb  = Wb + (size_t)QKV_DIM*D_MODEL;  // V^T [16*64, 2048] (own slot)
  u16* QKVb = (u16*)d_out;                   // QKV scratch [4096,3072] bf16

  const int nx  = MTOT*D_MODEL;
  const int nwq = D_MODEL*D_MODEL;
  const int nwk = 512*D_MODEL;
  const float QSCL = 0.125f * 1.44269504f;   // softmax scale * log2(e)

  cvt_bf16<<<nx/2048, 256, 0, stream>>>(x, xb, nx, 1.0f);
  cvt_bf16<<<nwq/2048, 256, 0, stream>>>(Wq, Wb, nwq, QSCL);
  cvt_bf16<<<nwk/2048, 256, 0, stream>>>(Wk, Wb + (size_t)D_MODEL*D_MODEL, nwk, 1.0f);
  cvt_bf16<<<nwk/2048, 256, 0, stream>>>(Wv, Wb + (size_t)2560*D_MODEL, nwk, 1.0f);
  gemm_bt<false><<<dim3(QKV_DIM/128, MTOT/128), 256, 0, stream>>>(xb, Wb, QKVb, MTOT, QKV_DIM, D_MODEL);
  vtrans<<<dim3(SEQ/64, 8, 2), 256, 0, stream>>>(QKVb, VTb);
  attn<<<dim3(SEQ/64, NUM_HEADS, 2), 256, 0, stream>>>(
      QKVb, QKVb + D_MODEL, VTb, xb, QKV_DIM, QKV_DIM);
  cvt_bf16<<<nwq/2048, 256, 0, stream>>>(Wo, Wb, nwq, 1.0f);
  gemm_bt<true><<<dim3(D_MODEL/128, MTOT/128), 256, 0, stream>>>(xb, Wb, (void*)out, MTOT, D_MODEL, D_MODEL);
}

// Round 9
// 343.228 us; speedup vs baseline: 1.7116x; 1.0102x over previous
//
#include <hip/hip_runtime.h>
#include <stdint.h>

// R15: attn is DS-pipe bound (per-wave-iter: 20 b128 DS ops ~240cy + 8-way
// bank conflicts on EVERY staged access; KP=72 padding gives (row+chunk)%8
// residues -> 1.3e7 conflict cycles, ~21us/CU). Fix per rule #21 / m214:
//  - kvtrans pre-builds K and V tiles (8KB per (b,hk,j)) in the exact
//    swizzled LDS image: chunk' = chunk ^ (row&7); V keeps the PV k-perm.
//    Output lives in Wb's Wq region (dead after gemm1, re-used by Wo cvt
//    after attn) -- zero extra workspace.
//  - attn stages via global_load_lds (linear dest = conflict-free, no
//    ds_write, no staging VALU/VGPR) and reads fragments with the same XOR.
//  LDS 18.4->16KB. Everything else = R14.

typedef unsigned short u16;
typedef short bf16x8 __attribute__((ext_vector_type(8)));
typedef float f32x4 __attribute__((ext_vector_type(4)));

#define D_MODEL 2048
#define QKV_DIM 3072
#define NUM_HEADS 32
#define HEAD_DIM 64
#define SEQ 2048
#define MTOT 4096

static __device__ __forceinline__ u16 f2bf(float f){
  uint32_t u = __builtin_bit_cast(uint32_t, f);
  u += 0x7FFFu + ((u >> 16) & 1u);
  return (u16)(u >> 16);
}

static __device__ __forceinline__ float exp2_fast(float x){
  float r;
  asm("v_exp_f32 %0, %1" : "=v"(r) : "v"(x));
  return r;
}

static __device__ __forceinline__ uint32_t cvt_pk_bf16(float lo, float hi){
  uint32_t r;
  asm("v_cvt_pk_bf16_f32 %0, %1, %2" : "=v"(r) : "v"(lo), "v"(hi));
  return r;
}

static __device__ __forceinline__ void gload16(const u16* g, u16* l){
  __builtin_amdgcn_global_load_lds(
      (__attribute__((address_space(1))) uint32_t*)(uintptr_t)g,
      (__attribute__((address_space(3))) uint32_t*)l,
      16, 0, 0);
}

__global__ __launch_bounds__(256)
void cvt_bf16(const float* __restrict__ in, u16* __restrict__ out, int n,
              float scl){
  const int i = (blockIdx.x * 256 + threadIdx.x) * 8;
  if (i >= n) return;
  float4 a = *(const float4*)(in + i);
  float4 b = *(const float4*)(in + i + 4);
  union { u16 h[8]; uint4 v; } t;
  t.h[0]=f2bf(a.x*scl); t.h[1]=f2bf(a.y*scl); t.h[2]=f2bf(a.z*scl); t.h[3]=f2bf(a.w*scl);
  t.h[4]=f2bf(b.x*scl); t.h[5]=f2bf(b.y*scl); t.h[6]=f2bf(b.z*scl); t.h[7]=f2bf(b.w*scl);
  *(uint4*)(out + i) = t.v;
}

// C[M,N] = A[M,K] @ B[N,K]^T (m97 structure, unchanged).
template <bool F32OUT>
__global__ __launch_bounds__(256)
void gemm_bt(const u16* __restrict__ A, const u16* __restrict__ B,
             void* __restrict__ Cv, int M, int N, int K){
  constexpr int BK = 32;
  __shared__ __attribute__((aligned(16))) u16 As[128*BK];
  __shared__ __attribute__((aligned(16))) u16 Bs[128*BK];
  const int tid  = threadIdx.x;
  const int wave = tid >> 6, lane = tid & 63;
  const int quad = lane >> 4, l16 = lane & 15;
  const int wrow = wave >> 1, wcol = wave & 1;
  const int m0 = blockIdx.y * 128, n0 = blockIdx.x * 128;
  const int srow = lane >> 2, scol = (lane & 3) * 8;

  const f32x4 zero = {0.f, 0.f, 0.f, 0.f};
  f32x4 acc[4][4];
#pragma unroll
  for (int i = 0; i < 4; i++)
#pragma unroll
    for (int j = 0; j < 4; j++) acc[i][j] = zero;

  for (int k0 = 0; k0 < K; k0 += BK){
#pragma unroll
    for (int t = 0; t < 2; t++){
      const int chunk = wave + t*4;
      gload16(A + (size_t)(m0 + chunk*16 + srow)*K + k0 + scol, As + chunk*16*BK);
      gload16(B + (size_t)(n0 + chunk*16 + srow)*K + k0 + scol, Bs + chunk*16*BK);
    }
    __syncthreads();
    bf16x8 af[4], bfr[4];
#pragma unroll
    for (int mi = 0; mi < 4; mi++)
      af[mi] = *(const bf16x8*)(As + (wrow*64 + mi*16 + l16)*BK + quad*8);
#pragma unroll
    for (int ni = 0; ni < 4; ni++)
      bfr[ni] = *(const bf16x8*)(Bs + (wcol*64 + ni*16 + l16)*BK + quad*8);
#pragma unroll
    for (int mi = 0; mi < 4; mi++)
#pragma unroll
      for (int ni = 0; ni < 4; ni++)
        acc[mi][ni] = __builtin_amdgcn_mfma_f32_16x16x32_bf16(af[mi], bfr[ni], acc[mi][ni], 0, 0, 0);
    __syncthreads();
  }
#pragma unroll
  for (int mi = 0; mi < 4; mi++)
#pragma unroll
    for (int ni = 0; ni < 4; ni++){
      const int col = n0 + wcol*64 + ni*16 + l16;
#pragma unroll
      for (int r = 0; r < 4; r++){
        const int row = m0 + wrow*64 + mi*16 + quad*4 + r;
        if constexpr (F32OUT)
          ((float*)Cv)[(size_t)row*N + col] = acc[mi][ni][r];
        else
          ((u16*)Cv)[(size_t)row*N + col] = f2bf(acc[mi][ni][r]);
      }
    }
}

// kvtrans: build per-(b,hk,j) 8KB K and V tiles in the exact (swizzled) LDS
// image attn wants. K[row=key][chunk c] stored at row*64 + (c^(row&7))*8.
// V is transposed (rows=d) with the PV k-permutation baked into the column
// order, then the same XOR swizzle.
__global__ __launch_bounds__(256)
void kvtrans(const u16* __restrict__ QKV, u16* __restrict__ Ksw,
             u16* __restrict__ Vsw){
  __shared__ u16 Ls[64*72];
  const int tid = threadIdx.x;
  const int st = blockIdx.x, hk = blockIdx.y, b = blockIdx.z;
  const size_t rb = (size_t)b * SEQ;
  const size_t tbase = ((size_t)(b*8 + hk)*32 + st) * 4096;

  // K tiles: gather rows, swizzle-store
#pragma unroll
  for (int t = 0; t < 2; t++){
    const int task = t*256 + tid;
    const int r = task >> 3, c = task & 7;
    uint4 kv = *(const uint4*)(QKV + (rb + st*64 + r)*QKV_DIM + 2048 + hk*HEAD_DIM + c*8);
    *(uint4*)(Ksw + tbase + r*64 + (size_t)((c ^ (r & 7)) * 8)) = kv;
  }
  // V tiles: stage rows into LDS, transpose+k-permute+swizzle out
#pragma unroll
  for (int t = 0; t < 2; t++){
    const int task = t*256 + tid;
    const int r = task >> 3, c = task & 7;
    *(uint4*)(Ls + r*72 + c*8) =
        *(const uint4*)(QKV + (rb + st*64 + r)*QKV_DIM + 2560 + hk*HEAD_DIM + c*8);
  }
  __syncthreads();
#pragma unroll
  for (int t = 0; t < 2; t++){
    const int task = t*256 + tid;
    const int d = task >> 3, sc = task & 7;
    union { u16 h[8]; uint4 v; } tmp;
#pragma unroll
    for (int e = 0; e < 8; e++){
      const int key = ((2*(sc>>2) + (e>>2))<<4) + ((sc&3)<<2) + (e&3);
      tmp.h[e] = Ls[key*72 + d];
    }
    *(uint4*)(Vsw + tbase + d*64 + (size_t)((sc ^ (d & 7)) * 8)) = tmp.v;
  }
}

// attn: swapped QK^T (scale pre-folded into Wq), in-register P, log2 softmax
// + defer-max, complement-balanced qt, gload_lds staging + XOR-swizzled reads.
__global__ __launch_bounds__(256)
void attn(const u16* __restrict__ Q, const u16* __restrict__ Ksw,
          const u16* __restrict__ Vsw, u16* __restrict__ O, int qs){
  __shared__ __attribute__((aligned(16))) u16 Ks[64*64];
  __shared__ __attribute__((aligned(16))) u16 Vt[64*64];
  const int tid = threadIdx.x;
  const int wave = tid >> 6, lane = tid & 63, quad = lane >> 4, l16 = lane & 15;
  const int g_ = (blockIdx.x + blockIdx.y) & 31;
  const int qt = blockIdx.z ? (31 - g_) : g_;
  const int h = blockIdx.y, b = blockIdx.z;
  const int hk = h >> 2;
  const size_t rb = (size_t)b * SEQ;
  const size_t hb = ((size_t)(b*8 + hk)) * 32;

  const int qrow = wave*16 + l16;   // this lane's q-row (swapped layout)
  const int sw = l16 & 7;           // XOR swizzle key for fragment reads

  bf16x8 qf[2];
  {
    const u16* qp = Q + (rb + qt*64 + wave*16 + l16)*qs + h*HEAD_DIM;
    qf[0] = *(const bf16x8*)(qp + quad*8);
    qf[1] = *(const bf16x8*)(qp + 32 + quad*8);
  }
  const f32x4 zero = {0.f, 0.f, 0.f, 0.f};
  f32x4 oacc[4];
#pragma unroll
  for (int i = 0; i < 4; i++) oacc[i] = zero;
  float m_i = -INFINITY;   // running max in log2 units
  float l_i = 0.f;

  for (int j = 0; j <= qt; ++j){
    // stage K/V tiles via global_load_lds: linear dest (conflict-free),
    // swizzle already baked into the global tile image.
    {
      const u16* kt = Ksw + (hb + j) * 4096;
      const u16* vt = Vsw + (hb + j) * 4096;
#pragma unroll
      for (int t = 0; t < 2; t++){
        const int ch = wave*2 + t;
        gload16(kt + ch*512 + lane*8, Ks + ch*512);
        gload16(vt + ch*512 + lane*8, Vt + ch*512);
      }
    }
    __syncthreads();

    // QK^T swapped: st[ni][r] = S2[key = j*64 + ni*16 + quad*4 + r][qrow l16]
    f32x4 st[4];
#pragma unroll
    for (int ni = 0; ni < 4; ni++){
      f32x4 s = zero;
#pragma unroll
      for (int ss = 0; ss < 2; ss++){
        bf16x8 kf = *(const bf16x8*)(Ks + ((ni*16 + l16) << 6) +
                                     (((ss*4 + quad) ^ sw) << 3));
        s = __builtin_amdgcn_mfma_f32_16x16x32_bf16(kf, qf[ss], s, 0, 0, 0);
      }
      st[ni] = s;
    }
    if (j == qt){
#pragma unroll
      for (int ni = 0; ni < 4; ni++)
#pragma unroll
        for (int r = 0; r < 4; r++)
          if (ni*16 + quad*4 + r > qrow) st[ni][r] = -INFINITY;
    }

    // row max (16 in-lane + 2 shfl across quads)
    float mx = fmaxf(fmaxf(fmaxf(st[0][0], st[0][1]), fmaxf(st[0][2], st[0][3])),
                     fmaxf(fmaxf(st[1][0], st[1][1]), fmaxf(st[1][2], st[1][3])));
    mx = fmaxf(mx, fmaxf(fmaxf(fmaxf(st[2][0], st[2][1]), fmaxf(st[2][2], st[2][3])),
                         fmaxf(fmaxf(st[3][0], st[3][1]), fmaxf(st[3][2], st[3][3]))));
    mx = fmaxf(mx, __shfl_xor(mx, 16));
    mx = fmaxf(mx, __shfl_xor(mx, 32));

    if (__all(mx <= m_i + 10.f)){
      // defer-max: keep m_i, alpha == 1, skip rescale entirely (p <= 2^10)
      float ps = 0.f;
#pragma unroll
      for (int ni = 0; ni < 4; ni++)
#pragma unroll
        for (int r = 0; r < 4; r++){
          const float p = exp2_fast(st[ni][r] - m_i);
          st[ni][r] = p;
          ps += p;
        }
      ps += __shfl_xor(ps, 16);
      ps += __shfl_xor(ps, 32);
      l_i += ps;
    } else {
      const float mn = fmaxf(m_i, mx);
      const float alpha = exp2_fast(m_i - mn);
      float ps = 0.f;
#pragma unroll
      for (int ni = 0; ni < 4; ni++)
#pragma unroll
        for (int r = 0; r < 4; r++){
          const float p = exp2_fast(st[ni][r] - mn);
          st[ni][r] = p;
          ps += p;
        }
      ps += __shfl_xor(ps, 16);
      ps += __shfl_xor(ps, 32);
      l_i = l_i*alpha + ps;
      m_i = mn;
      float ar[4];
#pragma unroll
      for (int r = 0; r < 4; r++) ar[r] = __shfl(alpha, quad*4 + r);
#pragma unroll
      for (int ci = 0; ci < 4; ci++)
#pragma unroll
        for (int r = 0; r < 4; r++) oacc[ci][r] *= ar[r];
    }

    // P stays in registers: packed bf16 via v_cvt_pk_bf16_f32.
    bf16x8 pfr[2];
#pragma unroll
    for (int ss = 0; ss < 2; ss++){
      union { uint32_t w[4]; bf16x8 v; } pk;
      pk.w[0] = cvt_pk_bf16(st[2*ss][0],   st[2*ss][1]);
      pk.w[1] = cvt_pk_bf16(st[2*ss][2],   st[2*ss][3]);
      pk.w[2] = cvt_pk_bf16(st[2*ss+1][0], st[2*ss+1][1]);
      pk.w[3] = cvt_pk_bf16(st[2*ss+1][2], st[2*ss+1][3]);
      pfr[ss] = pk.v;
    }

#pragma unroll
    for (int ss = 0; ss < 2; ss++)
#pragma unroll
      for (int ci = 0; ci < 4; ci++){
        bf16x8 vf = *(const bf16x8*)(Vt + ((ci*16 + l16) << 6) +
                                     (((ss*4 + quad) ^ sw) << 3));
        oacc[ci] = __builtin_amdgcn_mfma_f32_16x16x32_bf16(pfr[ss], vf, oacc[ci], 0, 0, 0);
      }
    __syncthreads();
  }

  // final: l_i lives in lane-space (row=l16); broadcast to row-space
  float lf[4];
#pragma unroll
  for (int r = 0; r < 4; r++) lf[r] = __shfl(l_i, quad*4 + r);
#pragma unroll
  for (int ci = 0; ci < 4; ci++)
#pragma unroll
    for (int r = 0; r < 4; r++){
      const size_t row = rb + qt*64 + wave*16 + quad*4 + r;
      O[row*D_MODEL + h*HEAD_DIM + ci*16 + l16] = f2bf(oacc[ci][r] / lf[r]);
    }
}

extern "C" void kernel_launch(void* const* d_in, const int* in_sizes, int n_in,
                              void* d_out, int out_size, void* d_ws, size_t ws_size,
                              hipStream_t stream){
  const float* x  = (const float*)d_in[0];
  const float* Wq = (const float*)d_in[1];
  const float* Wk = (const float*)d_in[2];
  const float* Wv = (const float*)d_in[3];
  const float* Wo = (const float*)d_in[4];
  float* out = (float*)d_out;

  u16* xb   = (u16*)d_ws;                    // x / later attn-out  [4096,2048]
  u16* Wb   = xb + (size_t)MTOT*D_MODEL;     // fused weights [3072,2048]
  u16* QKVb = (u16*)d_out;                   // QKV scratch [4096,3072] bf16
  // swizzled K/V tiles live in Wb's Wq region: dead after gemm1, overwritten
  // by the Wo cvt AFTER attn. 2M u16 each.
  u16* Kswz = Wb;
  u16* Vswz = Wb + (size_t)2*1024*1024;

  const int nx  = MTOT*D_MODEL;
  const int nwq = D_MODEL*D_MODEL;
  const int nwk = 512*D_MODEL;
  const float QSCL = 0.125f * 1.44269504f;   // softmax scale * log2(e)

  cvt_bf16<<<nx/2048, 256, 0, stream>>>(x, xb, nx, 1.0f);
  cvt_bf16<<<nwq/2048, 256, 0, stream>>>(Wq, Wb, nwq, QSCL);
  cvt_bf16<<<nwk/2048, 256, 0, stream>>>(Wk, Wb + (size_t)D_MODEL*D_MODEL, nwk, 1.0f);
  cvt_bf16<<<nwk/2048, 256, 0, stream>>>(Wv, Wb + (size_t)2560*D_MODEL, nwk, 1.0f);
  gemm_bt<false><<<dim3(QKV_DIM/128, MTOT/128), 256, 0, stream>>>(xb, Wb, QKVb, MTOT, QKV_DIM, D_MODEL);
  kvtrans<<<dim3(SEQ/64, 8, 2), 256, 0, stream>>>(QKVb, Kswz, Vswz);
  attn<<<dim3(SEQ/64, NUM_HEADS, 2), 256, 0, stream>>>(
      QKVb, Kswz, Vswz, xb, QKV_DIM);
  cvt_bf16<<<nwq/2048, 256, 0, stream>>>(Wo, Wb, nwq, 1.0f);
  gemm_bt<true><<<dim3(D_MODEL/128, MTOT/128), 256, 0, stream>>>(xb, Wb, (void*)out, MTOT, D_MODEL, D_MODEL);
}

// Round 11
// 341.361 us; speedup vs baseline: 1.7210x; 1.0055x over previous
//
#include <hip/hip_runtime.h>
#include <stdint.h>

// R17 = R16 resubmitted verbatim (R16's bench failed on container
// acquisition, not on the kernel: no compile/correctness/timeout evidence).
// R16: base = R15 except attn K/V LDS is DOUBLE-BUFFERED (T3-lite):
// one barrier per iteration; gload_lds for tile j+1 issues right after the
// barrier and lands in buf^1 while compute runs on buf. The vmcnt(0) drain
// folded into the next barrier occurs AFTER ~900cy of compute has covered
// the ~400cy load latency. Rationale: R15 zeroed bank conflicts but attn
// stayed latency-bound (MFMA 14.5, VALU 47.5, occupancy 25% => ~2 blocks/CU
// effective TLP; 1818cy/iter vs ~900cy compute content -- the gap is naked
// stage latency + 2 barriers). LDS 16->32KB (cap 5 blocks/CU > measured 2).

typedef unsigned short u16;
typedef short bf16x8 __attribute__((ext_vector_type(8)));
typedef float f32x4 __attribute__((ext_vector_type(4)));

#define D_MODEL 2048
#define QKV_DIM 3072
#define NUM_HEADS 32
#define HEAD_DIM 64
#define SEQ 2048
#define MTOT 4096

static __device__ __forceinline__ u16 f2bf(float f){
  uint32_t u = __builtin_bit_cast(uint32_t, f);
  u += 0x7FFFu + ((u >> 16) & 1u);
  return (u16)(u >> 16);
}

static __device__ __forceinline__ float exp2_fast(float x){
  float r;
  asm("v_exp_f32 %0, %1" : "=v"(r) : "v"(x));
  return r;
}

static __device__ __forceinline__ uint32_t cvt_pk_bf16(float lo, float hi){
  uint32_t r;
  asm("v_cvt_pk_bf16_f32 %0, %1, %2" : "=v"(r) : "v"(lo), "v"(hi));
  return r;
}

static __device__ __forceinline__ void gload16(const u16* g, u16* l){
  __builtin_amdgcn_global_load_lds(
      (__attribute__((address_space(1))) uint32_t*)(uintptr_t)g,
      (__attribute__((address_space(3))) uint32_t*)l,
      16, 0, 0);
}

__global__ __launch_bounds__(256)
void cvt_bf16(const float* __restrict__ in, u16* __restrict__ out, int n,
              float scl){
  const int i = (blockIdx.x * 256 + threadIdx.x) * 8;
  if (i >= n) return;
  float4 a = *(const float4*)(in + i);
  float4 b = *(const float4*)(in + i + 4);
  union { u16 h[8]; uint4 v; } t;
  t.h[0]=f2bf(a.x*scl); t.h[1]=f2bf(a.y*scl); t.h[2]=f2bf(a.z*scl); t.h[3]=f2bf(a.w*scl);
  t.h[4]=f2bf(b.x*scl); t.h[5]=f2bf(b.y*scl); t.h[6]=f2bf(b.z*scl); t.h[7]=f2bf(b.w*scl);
  *(uint4*)(out + i) = t.v;
}

// C[M,N] = A[M,K] @ B[N,K]^T (m97 structure, unchanged).
template <bool F32OUT>
__global__ __launch_bounds__(256)
void gemm_bt(const u16* __restrict__ A, const u16* __restrict__ B,
             void* __restrict__ Cv, int M, int N, int K){
  constexpr int BK = 32;
  __shared__ __attribute__((aligned(16))) u16 As[128*BK];
  __shared__ __attribute__((aligned(16))) u16 Bs[128*BK];
  const int tid  = threadIdx.x;
  const int wave = tid >> 6, lane = tid & 63;
  const int quad = lane >> 4, l16 = lane & 15;
  const int wrow = wave >> 1, wcol = wave & 1;
  const int m0 = blockIdx.y * 128, n0 = blockIdx.x * 128;
  const int srow = lane >> 2, scol = (lane & 3) * 8;

  const f32x4 zero = {0.f, 0.f, 0.f, 0.f};
  f32x4 acc[4][4];
#pragma unroll
  for (int i = 0; i < 4; i++)
#pragma unroll
    for (int j = 0; j < 4; j++) acc[i][j] = zero;

  for (int k0 = 0; k0 < K; k0 += BK){
#pragma unroll
    for (int t = 0; t < 2; t++){
      const int chunk = wave + t*4;
      gload16(A + (size_t)(m0 + chunk*16 + srow)*K + k0 + scol, As + chunk*16*BK);
      gload16(B + (size_t)(n0 + chunk*16 + srow)*K + k0 + scol, Bs + chunk*16*BK);
    }
    __syncthreads();
    bf16x8 af[4], bfr[4];
#pragma unroll
    for (int mi = 0; mi < 4; mi++)
      af[mi] = *(const bf16x8*)(As + (wrow*64 + mi*16 + l16)*BK + quad*8);
#pragma unroll
    for (int ni = 0; ni < 4; ni++)
      bfr[ni] = *(const bf16x8*)(Bs + (wcol*64 + ni*16 + l16)*BK + quad*8);
#pragma unroll
    for (int mi = 0; mi < 4; mi++)
#pragma unroll
      for (int ni = 0; ni < 4; ni++)
        acc[mi][ni] = __builtin_amdgcn_mfma_f32_16x16x32_bf16(af[mi], bfr[ni], acc[mi][ni], 0, 0, 0);
    __syncthreads();
  }
#pragma unroll
  for (int mi = 0; mi < 4; mi++)
#pragma unroll
    for (int ni = 0; ni < 4; ni++){
      const int col = n0 + wcol*64 + ni*16 + l16;
#pragma unroll
      for (int r = 0; r < 4; r++){
        const int row = m0 + wrow*64 + mi*16 + quad*4 + r;
        if constexpr (F32OUT)
          ((float*)Cv)[(size_t)row*N + col] = acc[mi][ni][r];
        else
          ((u16*)Cv)[(size_t)row*N + col] = f2bf(acc[mi][ni][r]);
      }
    }
}

// kvtrans: build per-(b,hk,j) 8KB K and V tiles in the exact (swizzled) LDS
// image attn wants. K[row=key][chunk c] stored at row*64 + (c^(row&7))*8.
// V is transposed (rows=d) with the PV k-permutation baked into the column
// order, then the same XOR swizzle.
__global__ __launch_bounds__(256)
void kvtrans(const u16* __restrict__ QKV, u16* __restrict__ Ksw,
             u16* __restrict__ Vsw){
  __shared__ u16 Ls[64*72];
  const int tid = threadIdx.x;
  const int st = blockIdx.x, hk = blockIdx.y, b = blockIdx.z;
  const size_t rb = (size_t)b * SEQ;
  const size_t tbase = ((size_t)(b*8 + hk)*32 + st) * 4096;

  // K tiles: gather rows, swizzle-store
#pragma unroll
  for (int t = 0; t < 2; t++){
    const int task = t*256 + tid;
    const int r = task >> 3, c = task & 7;
    uint4 kv = *(const uint4*)(QKV + (rb + st*64 + r)*QKV_DIM + 2048 + hk*HEAD_DIM + c*8);
    *(uint4*)(Ksw + tbase + r*64 + (size_t)((c ^ (r & 7)) * 8)) = kv;
  }
  // V tiles: stage rows into LDS, transpose+k-permute+swizzle out
#pragma unroll
  for (int t = 0; t < 2; t++){
    const int task = t*256 + tid;
    const int r = task >> 3, c = task & 7;
    *(uint4*)(Ls + r*72 + c*8) =
        *(const uint4*)(QKV + (rb + st*64 + r)*QKV_DIM + 2560 + hk*HEAD_DIM + c*8);
  }
  __syncthreads();
#pragma unroll
  for (int t = 0; t < 2; t++){
    const int task = t*256 + tid;
    const int d = task >> 3, sc = task & 7;
    union { u16 h[8]; uint4 v; } tmp;
#pragma unroll
    for (int e = 0; e < 8; e++){
      const int key = ((2*(sc>>2) + (e>>2))<<4) + ((sc&3)<<2) + (e&3);
      tmp.h[e] = Ls[key*72 + d];
    }
    *(uint4*)(Vsw + tbase + d*64 + (size_t)((sc ^ (d & 7)) * 8)) = tmp.v;
  }
}

// attn: swapped QK^T, in-register P, log2 softmax + defer-max,
// complement-balanced qt, DOUBLE-BUFFERED gload_lds staging, XOR reads.
__global__ __launch_bounds__(256)
void attn(const u16* __restrict__ Q, const u16* __restrict__ Ksw,
          const u16* __restrict__ Vsw, u16* __restrict__ O, int qs){
  __shared__ __attribute__((aligned(16))) u16 Ks[2][64*64];
  __shared__ __attribute__((aligned(16))) u16 Vt[2][64*64];
  const int tid = threadIdx.x;
  const int wave = tid >> 6, lane = tid & 63, quad = lane >> 4, l16 = lane & 15;
  const int g_ = (blockIdx.x + blockIdx.y) & 31;
  const int qt = blockIdx.z ? (31 - g_) : g_;
  const int h = blockIdx.y, b = blockIdx.z;
  const int hk = h >> 2;
  const size_t rb = (size_t)b * SEQ;
  const size_t hb = ((size_t)(b*8 + hk)) * 32;

  const int qrow = wave*16 + l16;   // this lane's q-row (swapped layout)
  const int sw = l16 & 7;           // XOR swizzle key for fragment reads

  bf16x8 qf[2];
  {
    const u16* qp = Q + (rb + qt*64 + wave*16 + l16)*qs + h*HEAD_DIM;
    qf[0] = *(const bf16x8*)(qp + quad*8);
    qf[1] = *(const bf16x8*)(qp + 32 + quad*8);
  }
  const f32x4 zero = {0.f, 0.f, 0.f, 0.f};
  f32x4 oacc[4];
#pragma unroll
  for (int i = 0; i < 4; i++) oacc[i] = zero;
  float m_i = -INFINITY;   // running max in log2 units
  float l_i = 0.f;

  // prologue: stage tile 0 into buffer 0
  {
    const u16* kt = Ksw + hb * 4096;
    const u16* vt = Vsw + hb * 4096;
#pragma unroll
    for (int t = 0; t < 2; t++){
      const int ch = wave*2 + t;
      gload16(kt + ch*512 + lane*8, &Ks[0][ch*512]);
      gload16(vt + ch*512 + lane*8, &Vt[0][ch*512]);
    }
  }
  int cur = 0;

  for (int j = 0; j <= qt; ++j){
    // barrier: (a) buf[cur] staged & visible (vmcnt drained here, after a
    // full compute phase covered the latency); (b) all waves done reading
    // buf[cur^1] from iter j-1 -> safe to overwrite.
    __syncthreads();
    if (j < qt){
      const u16* kt = Ksw + (hb + j + 1) * 4096;
      const u16* vt = Vsw + (hb + j + 1) * 4096;
#pragma unroll
      for (int t = 0; t < 2; t++){
        const int ch = wave*2 + t;
        gload16(kt + ch*512 + lane*8, &Ks[cur^1][ch*512]);
        gload16(vt + ch*512 + lane*8, &Vt[cur^1][ch*512]);
      }
    }
    const u16* Ksb = Ks[cur];
    const u16* Vtb = Vt[cur];

    // QK^T swapped: st[ni][r] = S2[key = j*64 + ni*16 + quad*4 + r][qrow l16]
    f32x4 st[4];
#pragma unroll
    for (int ni = 0; ni < 4; ni++){
      f32x4 s = zero;
#pragma unroll
      for (int ss = 0; ss < 2; ss++){
        bf16x8 kf = *(const bf16x8*)(Ksb + ((ni*16 + l16) << 6) +
                                     (((ss*4 + quad) ^ sw) << 3));
        s = __builtin_amdgcn_mfma_f32_16x16x32_bf16(kf, qf[ss], s, 0, 0, 0);
      }
      st[ni] = s;
    }
    if (j == qt){
#pragma unroll
      for (int ni = 0; ni < 4; ni++)
#pragma unroll
        for (int r = 0; r < 4; r++)
          if (ni*16 + quad*4 + r > qrow) st[ni][r] = -INFINITY;
    }

    // row max (16 in-lane + 2 shfl across quads)
    float mx = fmaxf(fmaxf(fmaxf(st[0][0], st[0][1]), fmaxf(st[0][2], st[0][3])),
                     fmaxf(fmaxf(st[1][0], st[1][1]), fmaxf(st[1][2], st[1][3])));
    mx = fmaxf(mx, fmaxf(fmaxf(fmaxf(st[2][0], st[2][1]), fmaxf(st[2][2], st[2][3])),
                         fmaxf(fmaxf(st[3][0], st[3][1]), fmaxf(st[3][2], st[3][3]))));
    mx = fmaxf(mx, __shfl_xor(mx, 16));
    mx = fmaxf(mx, __shfl_xor(mx, 32));

    if (__all(mx <= m_i + 10.f)){
      // defer-max: keep m_i, alpha == 1, skip rescale entirely (p <= 2^10)
      float ps = 0.f;
#pragma unroll
      for (int ni = 0; ni < 4; ni++)
#pragma unroll
        for (int r = 0; r < 4; r++){
          const float p = exp2_fast(st[ni][r] - m_i);
          st[ni][r] = p;
          ps += p;
        }
      ps += __shfl_xor(ps, 16);
      ps += __shfl_xor(ps, 32);
      l_i += ps;
    } else {
      const float mn = fmaxf(m_i, mx);
      const float alpha = exp2_fast(m_i - mn);
      float ps = 0.f;
#pragma unroll
      for (int ni = 0; ni < 4; ni++)
#pragma unroll
        for (int r = 0; r < 4; r++){
          const float p = exp2_fast(st[ni][r] - mn);
          st[ni][r] = p;
          ps += p;
        }
      ps += __shfl_xor(ps, 16);
      ps += __shfl_xor(ps, 32);
      l_i = l_i*alpha + ps;
      m_i = mn;
      float ar[4];
#pragma unroll
      for (int r = 0; r < 4; r++) ar[r] = __shfl(alpha, quad*4 + r);
#pragma unroll
      for (int ci = 0; ci < 4; ci++)
#pragma unroll
        for (int r = 0; r < 4; r++) oacc[ci][r] *= ar[r];
    }

    // P stays in registers: packed bf16 via v_cvt_pk_bf16_f32.
    bf16x8 pfr[2];
#pragma unroll
    for (int ss = 0; ss < 2; ss++){
      union { uint32_t w[4]; bf16x8 v; } pk;
      pk.w[0] = cvt_pk_bf16(st[2*ss][0],   st[2*ss][1]);
      pk.w[1] = cvt_pk_bf16(st[2*ss][2],   st[2*ss][3]);
      pk.w[2] = cvt_pk_bf16(st[2*ss+1][0], st[2*ss+1][1]);
      pk.w[3] = cvt_pk_bf16(st[2*ss+1][2], st[2*ss+1][3]);
      pfr[ss] = pk.v;
    }

#pragma unroll
    for (int ss = 0; ss < 2; ss++)
#pragma unroll
      for (int ci = 0; ci < 4; ci++){
        bf16x8 vf = *(const bf16x8*)(Vtb + ((ci*16 + l16) << 6) +
                                     (((ss*4 + quad) ^ sw) << 3));
        oacc[ci] = __builtin_amdgcn_mfma_f32_16x16x32_bf16(pfr[ss], vf, oacc[ci], 0, 0, 0);
      }
    cur ^= 1;
  }

  // final: l_i lives in lane-space (row=l16); broadcast to row-space
  float lf[4];
#pragma unroll
  for (int r = 0; r < 4; r++) lf[r] = __shfl(l_i, quad*4 + r);
#pragma unroll
  for (int ci = 0; ci < 4; ci++)
#pragma unroll
    for (int r = 0; r < 4; r++){
      const size_t row = rb + qt*64 + wave*16 + quad*4 + r;
      O[row*D_MODEL + h*HEAD_DIM + ci*16 + l16] = f2bf(oacc[ci][r] / lf[r]);
    }
}

extern "C" void kernel_launch(void* const* d_in, const int* in_sizes, int n_in,
                              void* d_out, int out_size, void* d_ws, size_t ws_size,
                              hipStream_t stream){
  const float* x  = (const float*)d_in[0];
  const float* Wq = (const float*)d_in[1];
  const float* Wk = (const float*)d_in[2];
  const float* Wv = (const float*)d_in[3];
  const float* Wo = (const float*)d_in[4];
  float* out = (float*)d_out;

  u16* xb   = (u16*)d_ws;                    // x / later attn-out  [4096,2048]
  u16* Wb   = xb + (size_t)MTOT*D_MODEL;     // fused weights [3072,2048]
  u16* QKVb = (u16*)d_out;                   // QKV scratch [4096,3072] bf16
  // swizzled K/V tiles live in Wb's Wq region: dead after gemm1, overwritten
  // by the Wo cvt AFTER attn. 2M u16 each.
  u16* Kswz = Wb;
  u16* Vswz = Wb + (size_t)2*1024*1024;

  const int nx  = MTOT*D_MODEL;
  const int nwq = D_MODEL*D_MODEL;
  const int nwk = 512*D_MODEL;
  const float QSCL = 0.125f * 1.44269504f;   // softmax scale * log2(e)

  cvt_bf16<<<nx/2048, 256, 0, stream>>>(x, xb, nx, 1.0f);
  cvt_bf16<<<nwq/2048, 256, 0, stream>>>(Wq, Wb, nwq, QSCL);
  cvt_bf16<<<nwk/2048, 256, 0, stream>>>(Wk, Wb + (size_t)D_MODEL*D_MODEL, nwk, 1.0f);
  cvt_bf16<<<nwk/2048, 256, 0, stream>>>(Wv, Wb + (size_t)2560*D_MODEL, nwk, 1.0f);
  gemm_bt<false><<<dim3(QKV_DIM/128, MTOT/128), 256, 0, stream>>>(xb, Wb, QKVb, MTOT, QKV_DIM, D_MODEL);
  kvtrans<<<dim3(SEQ/64, 8, 2), 256, 0, stream>>>(QKVb, Kswz, Vswz);
  attn<<<dim3(SEQ/64, NUM_HEADS, 2), 256, 0, stream>>>(
      QKVb, Kswz, Vswz, xb, QKV_DIM);
  cvt_bf16<<<nwq/2048, 256, 0, stream>>>(Wo, Wb, nwq, 1.0f);
  gemm_bt<true><<<dim3(D_MODEL/128, MTOT/128), 256, 0, stream>>>(xb, Wb, (void*)out, MTOT, D_MODEL, D_MODEL);
}